// Round 14
// baseline (294.831 us; speedup 1.0000x reference)
//
#include <hip/hip_runtime.h>
#include <stdint.h>

#define EPS 1e-8f

constexpr int HW = 16384;   // pixels per image (M and N dims)
constexpr int BM = 128;     // block M tile
constexpr int NG = 2048;    // n-group width per block (32 q-substeps of 64)

typedef __attribute__((ext_vector_type(4))) float floatx4;
typedef __attribute__((ext_vector_type(4))) int   intx4;
typedef __attribute__((ext_vector_type(8))) int   intx8;    // 32B = one f8f6f4 K=128 operand
typedef unsigned char u8;
typedef unsigned int u32;
typedef unsigned long long u64;

// Address-space-qualified pointers for global_load_lds (hipcc does NOT
// implicitly convert generic pointers to AS(1)/AS(3) builtin params).
typedef const __attribute__((address_space(1))) u32 gas_u32;
typedef __attribute__((address_space(3))) u32 las_u32;
__device__ inline void stage16(const void* g, void* l) {
    __builtin_amdgcn_global_load_lds((gas_u32*)g, (las_u32*)l, 16, 0, 0);
}

// HW packed fp8 e4m3 convert: 4 floats -> 4 bytes (2x v_cvt_pk_fp8_f32)
__device__ inline u32 pk4(float x0, float x1, float x2, float x3) {
    int t = __builtin_amdgcn_cvt_pk_fp8_f32(x0, x1, 0, false);
    t = __builtin_amdgcn_cvt_pk_fp8_f32(x2, x3, t, true);
    return (u32)t;
}

// ---------------------------------------------------------------------------
// Fragment layout (split-half, ds_read-conflict-free): pixel p, channel c:
//   g = p>>4 (16-px slab), r = p&15, kb = c>>7, q = (c>>5)&3, h = (c>>4)&1,
//   e8 = c&15;  byte = g*4096 + kb*2048 + h*1024 + (q*16+r)*16 + e8
// A 64-col slice (4 slabs) is 16KB CONTIGUOUS -> linear global_load_lds.
//
// PREP — R11-verified dense-store single pass. 512 blocks x 512 thr;
// thread = (pixel px, 16-channel unit cu) -> 16 fp8 bytes = ONE int4 store.
__global__ __launch_bounds__(512) void prep_kernel(const float* __restrict__ a,
                                                   const float* __restrict__ b,
                                                   float* __restrict__ sumsq_a,
                                                   float* __restrict__ sumsq_b,
                                                   u8* __restrict__ aF, u8* __restrict__ bF,
                                                   u64* __restrict__ packed,
                                                   float* __restrict__ out) {
    __shared__ float red[16][33];
    __shared__ float invb_sh[32];
    const int tid = threadIdx.x;
    const int px = tid & 31, cu = tid >> 5;      // 16 channel-units x 32 pixels
    const int p0 = blockIdx.x * 32;
    const int p = p0 + px;
    const int c0 = cu * 16;
    const u32 g = (u32)(p >> 4), r = (u32)(p & 15);
    const u32 sbase = g * 4096u + (u32)(cu >> 3) * 2048u + (u32)(cu & 1) * 1024u
                    + ((u32)((cu >> 1) & 3) * 16u + r) * 16u;

    if (blockIdx.x < 32) packed[(size_t)blockIdx.x * 512 + tid] = 0ull;
    if (blockIdx.x == 0 && tid == 0) *out = 0.f;

    // ---- b: 16 channels of one pixel into regs + sumsq partial
    float bv[16];
    float s = 0.f;
    #pragma unroll
    for (int e = 0; e < 16; ++e) {
        bv[e] = b[(size_t)(c0 + e) * HW + p];
        s += bv[e] * bv[e];
    }
    red[cu][px] = s;
    __syncthreads();
    if (tid < 32) {
        float B = 0.f;
        #pragma unroll
        for (int j = 0; j < 16; ++j) B += red[j][tid];
        sumsq_b[p0 + tid] = B;
        invb_sh[tid] = 1.0f / (sqrtf(B + EPS) + EPS);
    }
    __syncthreads();

    // normalized b fragment: ONE dense int4 store
    {
        const float inv = invb_sh[px];
        int4 W;
        W.x = (int)pk4(bv[0] * inv, bv[1] * inv, bv[2] * inv, bv[3] * inv);
        W.y = (int)pk4(bv[4] * inv, bv[5] * inv, bv[6] * inv, bv[7] * inv);
        W.z = (int)pk4(bv[8] * inv, bv[9] * inv, bv[10] * inv, bv[11] * inv);
        W.w = (int)pk4(bv[12] * inv, bv[13] * inv, bv[14] * inv, bv[15] * inv);
        *(int4*)(bF + sbase) = W;
    }

    // ---- a: raw fragment (dense int4) + sumsq partial
    {
        float av[16];
        s = 0.f;
        #pragma unroll
        for (int e = 0; e < 16; ++e) {
            av[e] = a[(size_t)(c0 + e) * HW + p];
            s += av[e] * av[e];
        }
        int4 W;
        W.x = (int)pk4(av[0], av[1], av[2], av[3]);
        W.y = (int)pk4(av[4], av[5], av[6], av[7]);
        W.z = (int)pk4(av[8], av[9], av[10], av[11]);
        W.w = (int)pk4(av[12], av[13], av[14], av[15]);
        *(int4*)(aF + sbase) = W;
    }
    red[cu][px] = s;                 // safe: all reduce reads happened before sync2
    __syncthreads();
    if (tid < 32) {
        float A = 0.f;
        #pragma unroll
        for (int j = 0; j < 16; ++j) A += red[j][tid];
        sumsq_a[p0 + tid] = A;
    }
}

// ---------------------------------------------------------------------------
// G: fused GEMM + argmax, MX-scaled fp8 (unit scales). Shell identical to
// the R8/R11-verified kernel (256 thr, (256,3), 2-buffer staging, wave tile
// 64x32). ONE delta (R13 calibration: ~400cy/qt non-overlapped overhead ==
// the 96-op argmax VALU tail, serial after acc): acc double-buffer
// accA/accB (STATIC names) — argmax of qt-1 issues between qt's ds_reads
// and mfma clusters, overlapping on the separate VALU pipe. +32 acc regs
// (AGPR side); spill tripwire = WRITE_SIZE > 8192KB.
#define MFMA1(A_, B_, C_) __builtin_amdgcn_mfma_scale_f32_16x16x128_f8f6f4( \
        (A_), (B_), (C_), 0, 0, 0, SCL, 0, SCL)

#define LDB(off_) __builtin_shufflevector(                                  \
        *(const intx4*)(Lb + (off_)), *(const intx4*)(Lb + (off_) + 1024),  \
        0, 1, 2, 3, 4, 5, 6, 7)

// compute one qt from buffer buf_ into acc_ (16 mfma, 2 setprio clusters)
#define MFMA_QT(acc_, buf_) do {                                            \
    const u8* Lb = &sB[buf_][(u32)(wn * 2) * 4096u + (u32)lane * 16u];      \
    intx8 Bk0n0 = LDB(0);                                                   \
    intx8 Bk0n1 = LDB(4096);                                                \
    __builtin_amdgcn_s_setprio(1);                                          \
    _Pragma("unroll")                                                       \
    for (int mi = 0; mi < 4; ++mi) {                                        \
        acc_[mi][0] = MFMA1(Afr[mi][0], Bk0n0, C64);                        \
        acc_[mi][1] = MFMA1(Afr[mi][0], Bk0n1, C64);                        \
    }                                                                       \
    __builtin_amdgcn_s_setprio(0);                                          \
    intx8 Bk1n0 = LDB(2048);                                                \
    intx8 Bk1n1 = LDB(4096 + 2048);                                         \
    __builtin_amdgcn_s_setprio(1);                                          \
    _Pragma("unroll")                                                       \
    for (int mi = 0; mi < 4; ++mi) {                                        \
        acc_[mi][0] = MFMA1(Afr[mi][1], Bk1n0, acc_[mi][0]);                \
        acc_[mi][1] = MFMA1(Afr[mi][1], Bk1n1, acc_[mi][1]);                \
    }                                                                       \
    __builtin_amdgcn_s_setprio(0);                                          \
} while (0)

#define ARGMAX_QT(acc_, qt_) do {                                           \
    const u32 qb_ = qbase + (u32)(qt_) * 64u;                               \
    _Pragma("unroll")                                                       \
    for (int mi = 0; mi < 4; ++mi) {                                        \
        _Pragma("unroll")                                                   \
        for (int ni = 0; ni < 2; ++ni) {                                    \
            const u32 qc_ = qb_ + (u32)(ni * 16);                           \
            _Pragma("unroll")                                               \
            for (int rr = 0; rr < 4; ++rr) {                                \
                float v_ = acc_[mi][ni][rr];                                \
                bool gt_ = v_ > bestv[mi][rr];                              \
                bestv[mi][rr] = gt_ ? v_ : bestv[mi][rr];                   \
                bestq[mi][rr] = gt_ ? qc_ : bestq[mi][rr];                  \
            }                                                               \
        }                                                                   \
    }                                                                       \
} while (0)

#define STAGE(buf_, qt_) do {                                               \
    const u8* gs_ = gQ + (u32)(qt_) * 16384u + so;                          \
    u8* ls_ = &sB[buf_][w * 4096];                                          \
    stage16(gs_,        ls_);                                               \
    stage16(gs_ + 1024, ls_ + 1024);                                        \
    stage16(gs_ + 2048, ls_ + 2048);                                        \
    stage16(gs_ + 3072, ls_ + 3072);                                        \
} while (0)

__global__ __launch_bounds__(256, 3) void gemm_argmax(const u8* __restrict__ aF,
                                                      const u8* __restrict__ bF,
                                                      u64* __restrict__ packed) {
    __shared__ u8 sB[2][16384];
    const int tid = threadIdx.x;
    const int w = tid >> 6, lane = tid & 63;
    const int q4 = lane >> 4, r15 = lane & 15;
    const int wm = w >> 1, wn = w & 1;

    const u32 bid = blockIdx.x;
    const u32 ng = bid & 7;          // n-group -> XCD (L2-resident B panel)
    const u32 mt = bid >> 3;         // 0..127 M tile
    const int p0 = (int)mt * BM;

    // A fragments resident: slab g = mt*8 + wm*4 + mi; two 16B halves at
    // g*4096 + kb*2048 + {0,1024} + lane*16
    const u8* gA = aF + (((size_t)(mt * 8 + wm * 4)) << 12) + (u32)lane * 16;
    intx8 Afr[4][2];
    #pragma unroll
    for (int mi = 0; mi < 4; ++mi)
        #pragma unroll
        for (int kb = 0; kb < 2; ++kb)
            Afr[mi][kb] = __builtin_shufflevector(
                *(const intx4*)(gA + (u32)(mi * 4096 + kb * 2048)),
                *(const intx4*)(gA + (u32)(mi * 4096 + kb * 2048 + 1024)),
                0, 1, 2, 3, 4, 5, 6, 7);

    // B panel for this ng: qt slice = gQ + qt*16384, 16KB contiguous
    const u8* gQ = bF + ((size_t)ng << 19);
    const u32 so = (u32)w * 4096u + (u32)lane * 16u;    // stage src offset (per-lane)

    float bestv[4][4];
    u32   bestq[4][4];
    #pragma unroll
    for (int mi = 0; mi < 4; ++mi)
        #pragma unroll
        for (int rr = 0; rr < 4; ++rr) { bestv[mi][rr] = -3.4e38f; bestq[mi][rr] = 0; }

    const u32 qbase = ng * 2048 + wn * 32 + (u32)r15;   // + qt*64 + ni*16
    const floatx4 C64 = {64.f, 64.f, 64.f, 64.f};
    const int SCL = 0x7F7F7F7F;      // E8M0 127 = 2^0 -> unit scale

    floatx4 accA[4][2], accB[4][2];

    // prologue
    STAGE(0, 0);
    __syncthreads();                 // buf0 (qt0) ready

    STAGE(1, 1);
    MFMA_QT(accA, 0);                // qt 0 -> accA
    __syncthreads();                 // buf1 (qt1) ready; buf0 reads done

    // main: even qt -> accA (buf0), odd qt -> accB (buf1); argmax lags 1 qt
    for (int e = 0; e < 32; e += 2) {
        const int o = e + 1;         // odd qt of this pair
        // odd qt o: stage o+1 -> buf0, compute accB from buf1, argmax accA(e)
        if (o + 1 < 32) STAGE(0, o + 1);
        MFMA_QT(accB, 1);
        ARGMAX_QT(accA, e);
        __syncthreads();

        if (o + 1 < 32) {
            // even qt e+2: stage e+3 -> buf1, compute accA from buf0, argmax accB(o)
            STAGE(1, o + 2);
            MFMA_QT(accA, 0);
            ARGMAX_QT(accB, o);
            __syncthreads();
        } else {
            ARGMAX_QT(accB, o);      // qt31 tail
        }
    }

    // final: pack (acc = s+64 > 0 -> float bits monotone as uint),
    // shuffle-reduce over r15 (stays in q4 group), 1 atomic/row/wave
    #pragma unroll
    for (int mi = 0; mi < 4; ++mi)
        #pragma unroll
        for (int rr = 0; rr < 4; ++rr) {
            u64 pk = ((u64)__float_as_uint(bestv[mi][rr]) << 32)
                   | (u64)(0xFFFFFFFFu - bestq[mi][rr]);
            #pragma unroll
            for (int d = 1; d < 16; d <<= 1) {
                u64 oV = __shfl_xor((unsigned long long)pk, d);
                pk = oV > pk ? oV : pk;
            }
            if (r15 == 0)
                atomicMax(&packed[p0 + wm * 64 + mi * 16 + q4 * 4 + rr], pk);
        }
}

// ---------------------------------------------------------------------------
// L: loss from the argmax's own similarity value (no gather).
// Decode: hi = bits(s+64) -> s = asfloat(hi) - 64; lo = ~q.
__global__ void loss_kernel(const u64* __restrict__ packed,
                            const float* __restrict__ sumsq_a, const float* __restrict__ sumsq_b,
                            float* __restrict__ out) {
    int p = blockIdx.x * 256 + threadIdx.x;
    u64 pk = packed[p];
    float s = __uint_as_float((u32)(pk >> 32)) - 64.0f;
    u32 q = 0xFFFFFFFFu - (u32)(pk & 0xFFFFFFFFull);
    float A = sumsq_a[p], B = sumsq_b[q];
    float dot = s * (sqrtf(B + EPS) + EPS);
    float cossim = dot / ((sqrtf(A) + EPS) * (sqrtf(B) + EPS));
    float v = (1.0f - cossim) * (1.0f / (float)HW);
    #pragma unroll
    for (int d = 1; d < 64; d <<= 1) v += __shfl_xor(v, d);
    if ((threadIdx.x & 63) == 0) atomicAdd(out, v);
}

// ---------------------------------------------------------------------------
extern "C" void kernel_launch(void* const* d_in, const int* in_sizes, int n_in,
                              void* d_out, int out_size, void* d_ws, size_t ws_size,
                              hipStream_t stream) {
    const float* a = (const float*)d_in[0];
    const float* b = (const float*)d_in[1];
    float* out = (float*)d_out;
    char* ws = (char*)d_ws;

    u8*    aF      = (u8*)ws;                                    // 4 MB
    u8*    bF      = (u8*)(ws + (size_t)4 * 1024 * 1024);        // 4 MB
    float* sumsq_a = (float*)(ws + (size_t)8 * 1024 * 1024);     // 64 KB
    float* sumsq_b = sumsq_a + HW;
    u64*   packed  = (u64*)(sumsq_b + HW);                       // 128 KB

    prep_kernel<<<dim3(HW / 32), 512, 0, stream>>>(a, b, sumsq_a, sumsq_b, aF, bF, packed, out);
    gemm_argmax<<<dim3((HW / BM) * (HW / NG)), 256, 0, stream>>>(aF, bF, packed);
    loss_kernel<<<dim3(HW / 256), 256, 0, stream>>>(packed, sumsq_a, sumsq_b, out);
}

// Round 15
// 147.783 us; speedup vs baseline: 1.9950x; 1.9950x over previous
//
#include <hip/hip_runtime.h>
#include <stdint.h>

#define EPS 1e-8f

constexpr int HW = 16384;   // pixels per image (M and N dims)
constexpr int BM = 128;     // block M tile
constexpr int NG = 2048;    // n-group width per block (32 q-substeps of 64)

typedef __attribute__((ext_vector_type(4))) float floatx4;
typedef __attribute__((ext_vector_type(4))) int   intx4;
typedef __attribute__((ext_vector_type(8))) int   intx8;    // 32B = one f8f6f4 K=128 operand
typedef unsigned char u8;
typedef unsigned int u32;
typedef unsigned long long u64;

// Address-space-qualified pointers for global_load_lds (hipcc does NOT
// implicitly convert generic pointers to AS(1)/AS(3) builtin params).
typedef const __attribute__((address_space(1))) u32 gas_u32;
typedef __attribute__((address_space(3))) u32 las_u32;
__device__ inline void stage16(const void* g, void* l) {
    __builtin_amdgcn_global_load_lds((gas_u32*)g, (las_u32*)l, 16, 0, 0);
}

// HW packed fp8 e4m3 convert: 4 floats -> 4 bytes (2x v_cvt_pk_fp8_f32)
__device__ inline u32 pk4(float x0, float x1, float x2, float x3) {
    int t = __builtin_amdgcn_cvt_pk_fp8_f32(x0, x1, 0, false);
    t = __builtin_amdgcn_cvt_pk_fp8_f32(x2, x3, t, true);
    return (u32)t;
}

// ---------------------------------------------------------------------------
// Fragment layout (split-half, ds_read-conflict-free): pixel p, channel c:
//   g = p>>4 (16-px slab), r = p&15, kb = c>>7, q = (c>>5)&3, h = (c>>4)&1,
//   e8 = c&15;  byte = g*4096 + kb*2048 + h*1024 + (q*16+r)*16 + e8
// A 64-col slice (4 slabs) is 16KB CONTIGUOUS -> linear global_load_lds.
//
// PREP — R11-verified dense-store single pass. 512 blocks x 512 thr;
// thread = (pixel px, 16-channel unit cu) -> 16 fp8 bytes = ONE int4 store.
__global__ __launch_bounds__(512) void prep_kernel(const float* __restrict__ a,
                                                   const float* __restrict__ b,
                                                   float* __restrict__ sumsq_a,
                                                   float* __restrict__ sumsq_b,
                                                   u8* __restrict__ aF, u8* __restrict__ bF,
                                                   u64* __restrict__ packed,
                                                   float* __restrict__ out) {
    __shared__ float red[16][33];
    __shared__ float invb_sh[32];
    const int tid = threadIdx.x;
    const int px = tid & 31, cu = tid >> 5;      // 16 channel-units x 32 pixels
    const int p0 = blockIdx.x * 32;
    const int p = p0 + px;
    const int c0 = cu * 16;
    const u32 g = (u32)(p >> 4), r = (u32)(p & 15);
    const u32 sbase = g * 4096u + (u32)(cu >> 3) * 2048u + (u32)(cu & 1) * 1024u
                    + ((u32)((cu >> 1) & 3) * 16u + r) * 16u;

    if (blockIdx.x < 32) packed[(size_t)blockIdx.x * 512 + tid] = 0ull;
    if (blockIdx.x == 0 && tid == 0) *out = 0.f;

    // ---- b: 16 channels of one pixel into regs + sumsq partial
    float bv[16];
    float s = 0.f;
    #pragma unroll
    for (int e = 0; e < 16; ++e) {
        bv[e] = b[(size_t)(c0 + e) * HW + p];
        s += bv[e] * bv[e];
    }
    red[cu][px] = s;
    __syncthreads();
    if (tid < 32) {
        float B = 0.f;
        #pragma unroll
        for (int j = 0; j < 16; ++j) B += red[j][tid];
        sumsq_b[p0 + tid] = B;
        invb_sh[tid] = 1.0f / (sqrtf(B + EPS) + EPS);
    }
    __syncthreads();

    // normalized b fragment: ONE dense int4 store
    {
        const float inv = invb_sh[px];
        int4 W;
        W.x = (int)pk4(bv[0] * inv, bv[1] * inv, bv[2] * inv, bv[3] * inv);
        W.y = (int)pk4(bv[4] * inv, bv[5] * inv, bv[6] * inv, bv[7] * inv);
        W.z = (int)pk4(bv[8] * inv, bv[9] * inv, bv[10] * inv, bv[11] * inv);
        W.w = (int)pk4(bv[12] * inv, bv[13] * inv, bv[14] * inv, bv[15] * inv);
        *(int4*)(bF + sbase) = W;
    }

    // ---- a: raw fragment (dense int4) + sumsq partial
    {
        float av[16];
        s = 0.f;
        #pragma unroll
        for (int e = 0; e < 16; ++e) {
            av[e] = a[(size_t)(c0 + e) * HW + p];
            s += av[e] * av[e];
        }
        int4 W;
        W.x = (int)pk4(av[0], av[1], av[2], av[3]);
        W.y = (int)pk4(av[4], av[5], av[6], av[7]);
        W.z = (int)pk4(av[8], av[9], av[10], av[11]);
        W.w = (int)pk4(av[12], av[13], av[14], av[15]);
        *(int4*)(aF + sbase) = W;
    }
    red[cu][px] = s;                 // safe: all reduce reads happened before sync2
    __syncthreads();
    if (tid < 32) {
        float A = 0.f;
        #pragma unroll
        for (int j = 0; j < 16; ++j) A += red[j][tid];
        sumsq_a[p0 + tid] = A;
    }
}

// ---------------------------------------------------------------------------
// G: fused GEMM + argmax, MX-scaled fp8 (unit scales). R14 schedule (acc
// double-buffer: argmax of qt-1 overlaps qt's mfma pipe time on the VALU
// pipe) with the launch-bounds fix. R14 post-mortem: measured VGPR caps are
// 256/N for __launch_bounds__(256,N) — (256,3) = 85-reg cap, which the R8
// structure saturated at 84; every restructure spilled for lack of ~10
// regs, not because the schedule was wrong. (256,2) -> 128-reg cap; state
// ~122 VGPR + 64 AGPR acc fits. HW occupancy at <=128 VGPR & 32KB LDS
// still allows 4 waves/SIMD (m69) — the bound caps the compiler, not HW.
// Spill tripwire: WRITE_SIZE > 8192KB.
#define MFMA1(A_, B_, C_) __builtin_amdgcn_mfma_scale_f32_16x16x128_f8f6f4( \
        (A_), (B_), (C_), 0, 0, 0, SCL, 0, SCL)

#define LDB(off_) __builtin_shufflevector(                                  \
        *(const intx4*)(Lb + (off_)), *(const intx4*)(Lb + (off_) + 1024),  \
        0, 1, 2, 3, 4, 5, 6, 7)

// compute one qt from buffer buf_ into acc_ (16 mfma, 2 setprio clusters)
#define MFMA_QT(acc_, buf_) do {                                            \
    const u8* Lb = &sB[buf_][(u32)(wn * 2) * 4096u + (u32)lane * 16u];      \
    intx8 Bk0n0 = LDB(0);                                                   \
    intx8 Bk0n1 = LDB(4096);                                                \
    __builtin_amdgcn_s_setprio(1);                                          \
    _Pragma("unroll")                                                       \
    for (int mi = 0; mi < 4; ++mi) {                                        \
        acc_[mi][0] = MFMA1(Afr[mi][0], Bk0n0, C64);                        \
        acc_[mi][1] = MFMA1(Afr[mi][0], Bk0n1, C64);                        \
    }                                                                       \
    __builtin_amdgcn_s_setprio(0);                                          \
    intx8 Bk1n0 = LDB(2048);                                                \
    intx8 Bk1n1 = LDB(4096 + 2048);                                         \
    __builtin_amdgcn_s_setprio(1);                                          \
    _Pragma("unroll")                                                       \
    for (int mi = 0; mi < 4; ++mi) {                                        \
        acc_[mi][0] = MFMA1(Afr[mi][1], Bk1n0, acc_[mi][0]);                \
        acc_[mi][1] = MFMA1(Afr[mi][1], Bk1n1, acc_[mi][1]);                \
    }                                                                       \
    __builtin_amdgcn_s_setprio(0);                                          \
} while (0)

#define ARGMAX_QT(acc_, qt_) do {                                           \
    const u32 qb_ = qbase + (u32)(qt_) * 64u;                               \
    _Pragma("unroll")                                                       \
    for (int mi = 0; mi < 4; ++mi) {                                        \
        _Pragma("unroll")                                                   \
        for (int ni = 0; ni < 2; ++ni) {                                    \
            const u32 qc_ = qb_ + (u32)(ni * 16);                           \
            _Pragma("unroll")                                               \
            for (int rr = 0; rr < 4; ++rr) {                                \
                float v_ = acc_[mi][ni][rr];                                \
                bool gt_ = v_ > bestv[mi][rr];                              \
                bestv[mi][rr] = gt_ ? v_ : bestv[mi][rr];                   \
                bestq[mi][rr] = gt_ ? qc_ : bestq[mi][rr];                  \
            }                                                               \
        }                                                                   \
    }                                                                       \
} while (0)

#define STAGE(buf_, qt_) do {                                               \
    const u8* gs_ = gQ + (u32)(qt_) * 16384u + so;                          \
    u8* ls_ = &sB[buf_][w * 4096];                                          \
    stage16(gs_,        ls_);                                               \
    stage16(gs_ + 1024, ls_ + 1024);                                        \
    stage16(gs_ + 2048, ls_ + 2048);                                        \
    stage16(gs_ + 3072, ls_ + 3072);                                        \
} while (0)

__global__ __launch_bounds__(256, 2) void gemm_argmax(const u8* __restrict__ aF,
                                                      const u8* __restrict__ bF,
                                                      u64* __restrict__ packed) {
    __shared__ u8 sB[2][16384];
    const int tid = threadIdx.x;
    const int w = tid >> 6, lane = tid & 63;
    const int q4 = lane >> 4, r15 = lane & 15;
    const int wm = w >> 1, wn = w & 1;

    const u32 bid = blockIdx.x;
    const u32 ng = bid & 7;          // n-group -> XCD (L2-resident B panel)
    const u32 mt = bid >> 3;         // 0..127 M tile
    const int p0 = (int)mt * BM;

    // A fragments resident: slab g = mt*8 + wm*4 + mi; two 16B halves at
    // g*4096 + kb*2048 + {0,1024} + lane*16
    const u8* gA = aF + (((size_t)(mt * 8 + wm * 4)) << 12) + (u32)lane * 16;
    intx8 Afr[4][2];
    #pragma unroll
    for (int mi = 0; mi < 4; ++mi)
        #pragma unroll
        for (int kb = 0; kb < 2; ++kb)
            Afr[mi][kb] = __builtin_shufflevector(
                *(const intx4*)(gA + (u32)(mi * 4096 + kb * 2048)),
                *(const intx4*)(gA + (u32)(mi * 4096 + kb * 2048 + 1024)),
                0, 1, 2, 3, 4, 5, 6, 7);

    // B panel for this ng: qt slice = gQ + qt*16384, 16KB contiguous
    const u8* gQ = bF + ((size_t)ng << 19);
    const u32 so = (u32)w * 4096u + (u32)lane * 16u;    // stage src offset (per-lane)

    float bestv[4][4];
    u32   bestq[4][4];
    #pragma unroll
    for (int mi = 0; mi < 4; ++mi)
        #pragma unroll
        for (int rr = 0; rr < 4; ++rr) { bestv[mi][rr] = -3.4e38f; bestq[mi][rr] = 0; }

    const u32 qbase = ng * 2048 + wn * 32 + (u32)r15;   // + qt*64 + ni*16
    const floatx4 C64 = {64.f, 64.f, 64.f, 64.f};
    const int SCL = 0x7F7F7F7F;      // E8M0 127 = 2^0 -> unit scale

    floatx4 accA[4][2], accB[4][2];

    // prologue
    STAGE(0, 0);
    __syncthreads();                 // buf0 (qt0) ready

    STAGE(1, 1);
    MFMA_QT(accA, 0);                // qt 0 -> accA
    __syncthreads();                 // buf1 (qt1) ready; buf0 reads done

    // main: even qt -> accA (buf0), odd qt -> accB (buf1); argmax lags 1 qt
    for (int e = 0; e < 32; e += 2) {
        const int o = e + 1;         // odd qt of this pair
        // odd qt o: stage o+1 -> buf0, compute accB from buf1, argmax accA(e)
        if (o + 1 < 32) STAGE(0, o + 1);
        MFMA_QT(accB, 1);
        ARGMAX_QT(accA, e);
        __syncthreads();

        if (o + 1 < 32) {
            // even qt e+2: stage e+3 -> buf1, compute accA from buf0, argmax accB(o)
            STAGE(1, o + 2);
            MFMA_QT(accA, 0);
            ARGMAX_QT(accB, o);
            __syncthreads();
        } else {
            ARGMAX_QT(accB, o);      // qt31 tail
        }
    }

    // final: pack (acc = s+64 > 0 -> float bits monotone as uint),
    // shuffle-reduce over r15 (stays in q4 group), 1 atomic/row/wave
    #pragma unroll
    for (int mi = 0; mi < 4; ++mi)
        #pragma unroll
        for (int rr = 0; rr < 4; ++rr) {
            u64 pk = ((u64)__float_as_uint(bestv[mi][rr]) << 32)
                   | (u64)(0xFFFFFFFFu - bestq[mi][rr]);
            #pragma unroll
            for (int d = 1; d < 16; d <<= 1) {
                u64 oV = __shfl_xor((unsigned long long)pk, d);
                pk = oV > pk ? oV : pk;
            }
            if (r15 == 0)
                atomicMax(&packed[p0 + wm * 64 + mi * 16 + q4 * 4 + rr], pk);
        }
}

// ---------------------------------------------------------------------------
// L: loss from the argmax's own similarity value (no gather).
// Decode: hi = bits(s+64) -> s = asfloat(hi) - 64; lo = ~q.
__global__ void loss_kernel(const u64* __restrict__ packed,
                            const float* __restrict__ sumsq_a, const float* __restrict__ sumsq_b,
                            float* __restrict__ out) {
    int p = blockIdx.x * 256 + threadIdx.x;
    u64 pk = packed[p];
    float s = __uint_as_float((u32)(pk >> 32)) - 64.0f;
    u32 q = 0xFFFFFFFFu - (u32)(pk & 0xFFFFFFFFull);
    float A = sumsq_a[p], B = sumsq_b[q];
    float dot = s * (sqrtf(B + EPS) + EPS);
    float cossim = dot / ((sqrtf(A) + EPS) * (sqrtf(B) + EPS));
    float v = (1.0f - cossim) * (1.0f / (float)HW);
    #pragma unroll
    for (int d = 1; d < 64; d <<= 1) v += __shfl_xor(v, d);
    if ((threadIdx.x & 63) == 0) atomicAdd(out, v);
}

// ---------------------------------------------------------------------------
extern "C" void kernel_launch(void* const* d_in, const int* in_sizes, int n_in,
                              void* d_out, int out_size, void* d_ws, size_t ws_size,
                              hipStream_t stream) {
    const float* a = (const float*)d_in[0];
    const float* b = (const float*)d_in[1];
    float* out = (float*)d_out;
    char* ws = (char*)d_ws;

    u8*    aF      = (u8*)ws;                                    // 4 MB
    u8*    bF      = (u8*)(ws + (size_t)4 * 1024 * 1024);        // 4 MB
    float* sumsq_a = (float*)(ws + (size_t)8 * 1024 * 1024);     // 64 KB
    float* sumsq_b = sumsq_a + HW;
    u64*   packed  = (u64*)(sumsq_b + HW);                       // 128 KB

    prep_kernel<<<dim3(HW / 32), 512, 0, stream>>>(a, b, sumsq_a, sumsq_b, aF, bF, packed, out);
    gemm_argmax<<<dim3((HW / BM) * (HW / NG)), 256, 0, stream>>>(aF, bF, packed);
    loss_kernel<<<dim3(HW / 256), 256, 0, stream>>>(packed, sumsq_a, sumsq_b, out);
}

// Round 16
// 140.016 us; speedup vs baseline: 2.1057x; 1.0555x over previous
//
#include <hip/hip_runtime.h>
#include <stdint.h>

#define EPS 1e-8f

constexpr int HW = 16384;   // pixels per image (M and N dims)
constexpr int BM = 128;     // block M tile
constexpr int NG = 2048;    // n-group width per block (32 q-substeps of 64)

typedef __attribute__((ext_vector_type(4))) float floatx4;
typedef __attribute__((ext_vector_type(4))) int   intx4;
typedef __attribute__((ext_vector_type(8))) int   intx8;    // 32B = one f8f6f4 K=128 operand
typedef unsigned char u8;
typedef unsigned int u32;
typedef unsigned long long u64;

// Address-space-qualified pointers for global_load_lds (hipcc does NOT
// implicitly convert generic pointers to AS(1)/AS(3) builtin params).
typedef const __attribute__((address_space(1))) u32 gas_u32;
typedef __attribute__((address_space(3))) u32 las_u32;
__device__ inline void stage16(const void* g, void* l) {
    __builtin_amdgcn_global_load_lds((gas_u32*)g, (las_u32*)l, 16, 0, 0);
}

// HW packed fp8 e4m3 convert: 4 floats -> 4 bytes (2x v_cvt_pk_fp8_f32)
__device__ inline u32 pk4(float x0, float x1, float x2, float x3) {
    int t = __builtin_amdgcn_cvt_pk_fp8_f32(x0, x1, 0, false);
    t = __builtin_amdgcn_cvt_pk_fp8_f32(x2, x3, t, true);
    return (u32)t;
}

// ---------------------------------------------------------------------------
// Fragment layout (split-half, ds_read-conflict-free): pixel p, channel c:
//   g = p>>4 (16-px slab), r = p&15, kb = c>>7, q = (c>>5)&3, h = (c>>4)&1,
//   e8 = c&15;  byte = g*4096 + kb*2048 + h*1024 + (q*16+r)*16 + e8
// A 64-col slice (4 slabs) is 16KB CONTIGUOUS -> linear global_load_lds.
//
// PREP — R11-verified dense-store single pass. 512 blocks x 512 thr;
// thread = (pixel px, 16-channel unit cu) -> 16 fp8 bytes = ONE int4 store.
__global__ __launch_bounds__(512) void prep_kernel(const float* __restrict__ a,
                                                   const float* __restrict__ b,
                                                   float* __restrict__ sumsq_a,
                                                   float* __restrict__ sumsq_b,
                                                   u8* __restrict__ aF, u8* __restrict__ bF,
                                                   u64* __restrict__ packed,
                                                   float* __restrict__ out) {
    __shared__ float red[16][33];
    __shared__ float invb_sh[32];
    const int tid = threadIdx.x;
    const int px = tid & 31, cu = tid >> 5;      // 16 channel-units x 32 pixels
    const int p0 = blockIdx.x * 32;
    const int p = p0 + px;
    const int c0 = cu * 16;
    const u32 g = (u32)(p >> 4), r = (u32)(p & 15);
    const u32 sbase = g * 4096u + (u32)(cu >> 3) * 2048u + (u32)(cu & 1) * 1024u
                    + ((u32)((cu >> 1) & 3) * 16u + r) * 16u;

    if (blockIdx.x < 32) packed[(size_t)blockIdx.x * 512 + tid] = 0ull;
    if (blockIdx.x == 0 && tid == 0) *out = 0.f;

    // ---- b: 16 channels of one pixel into regs + sumsq partial
    float bv[16];
    float s = 0.f;
    #pragma unroll
    for (int e = 0; e < 16; ++e) {
        bv[e] = b[(size_t)(c0 + e) * HW + p];
        s += bv[e] * bv[e];
    }
    red[cu][px] = s;
    __syncthreads();
    if (tid < 32) {
        float B = 0.f;
        #pragma unroll
        for (int j = 0; j < 16; ++j) B += red[j][tid];
        sumsq_b[p0 + tid] = B;
        invb_sh[tid] = 1.0f / (sqrtf(B + EPS) + EPS);
    }
    __syncthreads();

    // normalized b fragment: ONE dense int4 store
    {
        const float inv = invb_sh[px];
        int4 W;
        W.x = (int)pk4(bv[0] * inv, bv[1] * inv, bv[2] * inv, bv[3] * inv);
        W.y = (int)pk4(bv[4] * inv, bv[5] * inv, bv[6] * inv, bv[7] * inv);
        W.z = (int)pk4(bv[8] * inv, bv[9] * inv, bv[10] * inv, bv[11] * inv);
        W.w = (int)pk4(bv[12] * inv, bv[13] * inv, bv[14] * inv, bv[15] * inv);
        *(int4*)(bF + sbase) = W;
    }

    // ---- a: raw fragment (dense int4) + sumsq partial
    {
        float av[16];
        s = 0.f;
        #pragma unroll
        for (int e = 0; e < 16; ++e) {
            av[e] = a[(size_t)(c0 + e) * HW + p];
            s += av[e] * av[e];
        }
        int4 W;
        W.x = (int)pk4(av[0], av[1], av[2], av[3]);
        W.y = (int)pk4(av[4], av[5], av[6], av[7]);
        W.z = (int)pk4(av[8], av[9], av[10], av[11]);
        W.w = (int)pk4(av[12], av[13], av[14], av[15]);
        *(int4*)(aF + sbase) = W;
    }
    red[cu][px] = s;                 // safe: all reduce reads happened before sync2
    __syncthreads();
    if (tid < 32) {
        float A = 0.f;
        #pragma unroll
        for (int j = 0; j < 16; ++j) A += red[j][tid];
        sumsq_a[p0 + tid] = A;
    }
}

// ---------------------------------------------------------------------------
// G: fused GEMM + argmax, MX-scaled fp8 (unit scales). R15 post-mortem:
// acc-dbuf (clean, no spill) changed NOTHING -> the invariant 400cy/qt cost
// is the per-qt vmcnt(0) drain inside __syncthreads (every structure kept
// it). This round removes it: R7's depth-3 LDS ring + raw s_barrier +
// counted s_waitcnt vmcnt(4) (T3/T4: tile t's loads retire while t+1's
// stay in flight; ~2 iterations of latency cover, no synchronous drain).
// R7 was CORRECT (passed) but ran under the (256,3)=85-reg cap and spilled
// 57MB; R14/R15 established the cap model and that (256,2)=128 regs runs
// clean (VGPR 108) with no perf loss from 2 blocks/CU. Single acc (R15:
// argmax overlap is worthless). FIFO: at iter t outstanding={t:4,t+1:4} ->
// vmcnt(4) retires exactly tile t; each wave waits its own loads before the
// barrier, so all quarters are ready after it. Slot (t+2)%3 is re-staged
// only after the barrier proving tile t-1 (same slot) reads completed.
// Spill tripwire: WRITE_SIZE > 8192KB.
#define MFMA1(A_, B_, C_) __builtin_amdgcn_mfma_scale_f32_16x16x128_f8f6f4( \
        (A_), (B_), (C_), 0, 0, 0, SCL, 0, SCL)

#define LDB(off_) __builtin_shufflevector(                                  \
        *(const intx4*)(Lb + (off_)), *(const intx4*)(Lb + (off_) + 1024),  \
        0, 1, 2, 3, 4, 5, 6, 7)

#define STAGE(slot_, qt_) do {                                              \
    const u8* gs_ = gQ + (u32)(qt_) * 16384u + so;                          \
    u8* ls_ = sB0 + (u32)(slot_) * 16384u + wso;                            \
    stage16(gs_,        ls_);                                               \
    stage16(gs_ + 1024, ls_ + 1024);                                        \
    stage16(gs_ + 2048, ls_ + 2048);                                        \
    stage16(gs_ + 3072, ls_ + 3072);                                        \
} while (0)

#define COMPUTE_QT(sc_, qc_) do {                                           \
    const u8* Lb = sB0 + (u32)(sc_) * 16384u                                \
                 + (u32)(wn * 2) * 4096u + (u32)lane * 16u;                 \
    floatx4 acc[4][2];                                                      \
    intx8 Bk0n0 = LDB(0);                                                   \
    intx8 Bk0n1 = LDB(4096);                                                \
    __builtin_amdgcn_s_setprio(1);                                          \
    _Pragma("unroll")                                                       \
    for (int mi = 0; mi < 4; ++mi) {                                        \
        acc[mi][0] = MFMA1(Afr[mi][0], Bk0n0, C64);                         \
        acc[mi][1] = MFMA1(Afr[mi][0], Bk0n1, C64);                         \
    }                                                                       \
    __builtin_amdgcn_s_setprio(0);                                          \
    intx8 Bk1n0 = LDB(2048);                                                \
    intx8 Bk1n1 = LDB(4096 + 2048);                                         \
    __builtin_amdgcn_s_setprio(1);                                          \
    _Pragma("unroll")                                                       \
    for (int mi = 0; mi < 4; ++mi) {                                        \
        acc[mi][0] = MFMA1(Afr[mi][1], Bk1n0, acc[mi][0]);                  \
        acc[mi][1] = MFMA1(Afr[mi][1], Bk1n1, acc[mi][1]);                  \
    }                                                                       \
    __builtin_amdgcn_s_setprio(0);                                          \
    _Pragma("unroll")                                                       \
    for (int mi = 0; mi < 4; ++mi) {                                        \
        _Pragma("unroll")                                                   \
        for (int ni = 0; ni < 2; ++ni) {                                    \
            const u32 qn_ = (qc_) + (u32)(ni * 16);                         \
            _Pragma("unroll")                                               \
            for (int rr = 0; rr < 4; ++rr) {                                \
                float v_ = acc[mi][ni][rr];                                 \
                bool gt_ = v_ > bestv[mi][rr];                              \
                bestv[mi][rr] = gt_ ? v_ : bestv[mi][rr];                   \
                bestq[mi][rr] = gt_ ? qn_ : bestq[mi][rr];                  \
            }                                                               \
        }                                                                   \
    }                                                                       \
} while (0)

__global__ __launch_bounds__(256, 2) void gemm_argmax(const u8* __restrict__ aF,
                                                      const u8* __restrict__ bF,
                                                      u64* __restrict__ packed) {
    __shared__ u8 sB[3][16384];     // depth-3 ring, 48KB; 2 blocks/CU = 96KB
    u8* sB0 = &sB[0][0];
    const int tid = threadIdx.x;
    const int w = tid >> 6, lane = tid & 63;
    const int q4 = lane >> 4, r15 = lane & 15;
    const int wm = w >> 1, wn = w & 1;     // 2m x 2n waves, wave tile 64x32

    const u32 bid = blockIdx.x;
    const u32 ng = bid & 7;          // n-group -> XCD (L2-resident B panel)
    const u32 mt = bid >> 3;         // 0..127 M tile
    const int p0 = (int)mt * BM;

    // A fragments resident: slab g = mt*8 + wm*4 + mi; two 16B halves at
    // g*4096 + kb*2048 + {0,1024} + lane*16
    const u8* gA = aF + (((size_t)(mt * 8 + wm * 4)) << 12) + (u32)lane * 16;
    intx8 Afr[4][2];
    #pragma unroll
    for (int mi = 0; mi < 4; ++mi)
        #pragma unroll
        for (int kb = 0; kb < 2; ++kb)
            Afr[mi][kb] = __builtin_shufflevector(
                *(const intx4*)(gA + (u32)(mi * 4096 + kb * 2048)),
                *(const intx4*)(gA + (u32)(mi * 4096 + kb * 2048 + 1024)),
                0, 1, 2, 3, 4, 5, 6, 7);

    // B panel for this ng: qt slice = gQ + qt*16384, 16KB contiguous
    const u8* gQ = bF + ((size_t)ng << 19);
    const u32 so  = (u32)w * 4096u + (u32)lane * 16u;   // stage src offset
    const u32 wso = (u32)w * 4096u;                      // LDS dest (wave-uniform)

    float bestv[4][4];
    u32   bestq[4][4];
    #pragma unroll
    for (int mi = 0; mi < 4; ++mi)
        #pragma unroll
        for (int rr = 0; rr < 4; ++rr) { bestv[mi][rr] = -3.4e38f; bestq[mi][rr] = 0; }

    u32 qcur = ng * 2048 + wn * 32 + (u32)r15;   // running col id (ni0); ni1 = +16
    const floatx4 C64 = {64.f, 64.f, 64.f, 64.f};
    const int SCL = 0x7F7F7F7F;      // E8M0 127 = 2^0 -> unit scale

    // prologue: tiles 0,1 in flight (8 loads/wave)
    STAGE(0, 0);
    STAGE(1, 1);

    int sc = 0;                      // slot of tile t
    for (int t = 0; t < 31; ++t) {
        asm volatile("s_waitcnt vmcnt(4)" ::: "memory");   // tile t landed; t+1 in flight
        __builtin_amdgcn_sched_barrier(0);
        __builtin_amdgcn_s_barrier();                      // all waves: t ready, t-1 reads done
        if (t < 30) {
            const int s2 = sc == 0 ? 2 : sc - 1;           // (t+2)%3
            STAGE(s2, t + 2);
        }
        COMPUTE_QT(sc, qcur);
        qcur += 64u;
        sc = sc == 2 ? 0 : sc + 1;
    }
    asm volatile("s_waitcnt vmcnt(0)" ::: "memory");
    __builtin_amdgcn_sched_barrier(0);
    __builtin_amdgcn_s_barrier();
    COMPUTE_QT(sc, qcur);            // tile 31

    // final: pack (acc = s+64 > 0 -> float bits monotone as uint),
    // shuffle-reduce over r15 (stays in q4 group), 1 atomic/row/wave
    #pragma unroll
    for (int mi = 0; mi < 4; ++mi)
        #pragma unroll
        for (int rr = 0; rr < 4; ++rr) {
            u64 pk = ((u64)__float_as_uint(bestv[mi][rr]) << 32)
                   | (u64)(0xFFFFFFFFu - bestq[mi][rr]);
            #pragma unroll
            for (int d = 1; d < 16; d <<= 1) {
                u64 oV = __shfl_xor((unsigned long long)pk, d);
                pk = oV > pk ? oV : pk;
            }
            if (r15 == 0)
                atomicMax(&packed[p0 + wm * 64 + mi * 16 + q4 * 4 + rr], pk);
        }
}

// ---------------------------------------------------------------------------
// L: loss from the argmax's own similarity value (no gather).
// Decode: hi = bits(s+64) -> s = asfloat(hi) - 64; lo = ~q.
__global__ void loss_kernel(const u64* __restrict__ packed,
                            const float* __restrict__ sumsq_a, const float* __restrict__ sumsq_b,
                            float* __restrict__ out) {
    int p = blockIdx.x * 256 + threadIdx.x;
    u64 pk = packed[p];
    float s = __uint_as_float((u32)(pk >> 32)) - 64.0f;
    u32 q = 0xFFFFFFFFu - (u32)(pk & 0xFFFFFFFFull);
    float A = sumsq_a[p], B = sumsq_b[q];
    float dot = s * (sqrtf(B + EPS) + EPS);
    float cossim = dot / ((sqrtf(A) + EPS) * (sqrtf(B) + EPS));
    float v = (1.0f - cossim) * (1.0f / (float)HW);
    #pragma unroll
    for (int d = 1; d < 64; d <<= 1) v += __shfl_xor(v, d);
    if ((threadIdx.x & 63) == 0) atomicAdd(out, v);
}

// ---------------------------------------------------------------------------
extern "C" void kernel_launch(void* const* d_in, const int* in_sizes, int n_in,
                              void* d_out, int out_size, void* d_ws, size_t ws_size,
                              hipStream_t stream) {
    const float* a = (const float*)d_in[0];
    const float* b = (const float*)d_in[1];
    float* out = (float*)d_out;
    char* ws = (char*)d_ws;

    u8*    aF      = (u8*)ws;                                    // 4 MB
    u8*    bF      = (u8*)(ws + (size_t)4 * 1024 * 1024);        // 4 MB
    float* sumsq_a = (float*)(ws + (size_t)8 * 1024 * 1024);     // 64 KB
    float* sumsq_b = sumsq_a + HW;
    u64*   packed  = (u64*)(sumsq_b + HW);                       // 128 KB

    prep_kernel<<<dim3(HW / 32), 512, 0, stream>>>(a, b, sumsq_a, sumsq_b, aF, bF, packed, out);
    gemm_argmax<<<dim3((HW / BM) * (HW / NG)), 256, 0, stream>>>(aF, bF, packed);
    loss_kernel<<<dim3(HW / 256), 256, 0, stream>>>(packed, sumsq_a, sumsq_b, out);
}